// Round 3
// baseline (158.599 us; speedup 1.0000x reference)
//
#include <hip/hip_runtime.h>
#include <hip/hip_bf16.h>
#include <math.h>

#define BB 8
#define TT 2048
#define CC 1024
#define HH 64
#define BT (BB * TT)   // 16384 rows

typedef __attribute__((ext_vector_type(8))) short short8;   // bf16 x8 MFMA frag
typedef __attribute__((ext_vector_type(4))) float floatx4;  // MFMA acc

static __device__ inline ushort f2bf(float f) {
    __hip_bfloat16 h = __float2bfloat16(f);
    return *reinterpret_cast<ushort*>(&h);
}
static __device__ inline unsigned int f2bf2(float lo, float hi) {
    __hip_bfloat162 h = __float22bfloat162_rn(make_float2(lo, hi));
    return *reinterpret_cast<unsigned int*>(&h);
}
static __device__ inline float bf2f(ushort u) {
    union { unsigned int i; float f; } c;
    c.i = ((unsigned int)u) << 16;
    return c.f;
}

// ---------------------------------------------------------------------------
// Kernel 0: W prep (coalesced).  W[k][n] fp32 -> WbT[m][n][k] bf16.
// ---------------------------------------------------------------------------
__global__ __launch_bounds__(256) void wprep_kernel(
    const float* __restrict__ Wq, const float* __restrict__ Wk,
    const float* __restrict__ Wv, ushort* __restrict__ WbT)
{
    __shared__ float ws_[64 * 65];
    const int m  = blockIdx.x >> 4;          // 0..2
    const int kb = (blockIdx.x & 15) * 64;   // 0..960
    const float* W = (m == 0) ? Wq : (m == 1) ? Wk : Wv;
    const int t  = threadIdx.x;
    const int lr = t >> 4, lc = (t & 15) * 4;
    #pragma unroll
    for (int i = 0; i < 4; ++i) {
        const int row = lr + i * 16;
        float4 v = *(const float4*)&W[(size_t)(kb + row) * HH + lc];
        ws_[row * 65 + lc + 0] = v.x; ws_[row * 65 + lc + 1] = v.y;
        ws_[row * 65 + lc + 2] = v.z; ws_[row * 65 + lc + 3] = v.w;
    }
    __syncthreads();
    const int n = t & 63, kseg = t >> 6;     // kseg 0..3 -> 16 k each
    union { ushort s[16]; uint4 q[2]; } u;
    #pragma unroll
    for (int j = 0; j < 16; ++j)
        u.s[j] = f2bf(ws_[(kseg * 16 + j) * 65 + n]);
    ushort* dst = &WbT[(size_t)(m * 64 + n) * 1024 + kb + kseg * 16];
    *(uint4*)&dst[0] = u.q[0];
    *(uint4*)&dst[8] = u.q[1];
}

// ---------------------------------------------------------------------------
// Kernel 1: QKV via bf16 MFMA — BARRIER-FREE this round.
// Each wave builds its own A-frags directly from global x (all 4 waves read
// the same 8KB tile -> L1/L2 hits after first toucher).  No LDS, no
// __syncthreads -> no vmcnt(0) drains; waves drift and self-overlap.
// ---------------------------------------------------------------------------
__global__ __launch_bounds__(256) void qkv_kernel(
    const float* __restrict__ x, const ushort* __restrict__ WbT,
    ushort* __restrict__ qb, ushort* __restrict__ kbS, ushort* __restrict__ vS)
{
    const int row0 = blockIdx.x * 32;
    const int t    = threadIdx.x;
    const int w    = t >> 6;
    const int lane = t & 63;
    const int l16  = lane & 15;
    const int quad = lane >> 4;
    const int ct0  = w * 3;

    floatx4 acc[2][3];
    #pragma unroll
    for (int mt = 0; mt < 2; ++mt)
        #pragma unroll
        for (int c = 0; c < 3; ++c) acc[mt][c] = (floatx4){0.f, 0.f, 0.f, 0.f};

    // per-lane x base: row row0 + mt*16 + l16, col quad*8 (+p*32 +it*64)
    const float* xr0 = &x[(size_t)(row0 + l16) * CC + quad * 8];
    const float* xr1 = xr0 + 16 * CC;

    // depth-1 prefetch buffers: [mt*2+p][half]
    float4 xc[4][2], xn[4][2];
    #pragma unroll
    for (int mt = 0; mt < 2; ++mt)
        #pragma unroll
        for (int p = 0; p < 2; ++p) {
            const float* src = (mt ? xr1 : xr0) + p * 32;
            xc[mt * 2 + p][0] = *(const float4*)&src[0];
            xc[mt * 2 + p][1] = *(const float4*)&src[4];
        }

    short8 bfr[2][3], bnx[2][3];
    #pragma unroll
    for (int p = 0; p < 2; ++p)
        #pragma unroll
        for (int c = 0; c < 3; ++c)
            bfr[p][c] = *(const short8*)&WbT[(size_t)((ct0 + c) * 16 + l16) * 1024
                                             + p * 32 + quad * 8];

    for (int it = 0; it < 16; ++it) {
        // issue next-iter loads first (longest latency, no barrier will drain them)
        if (it < 15) {
            const int kn = (it + 1) * 64;
            #pragma unroll
            for (int mt = 0; mt < 2; ++mt)
                #pragma unroll
                for (int p = 0; p < 2; ++p) {
                    const float* src = (mt ? xr1 : xr0) + kn + p * 32;
                    xn[mt * 2 + p][0] = *(const float4*)&src[0];
                    xn[mt * 2 + p][1] = *(const float4*)&src[4];
                }
            #pragma unroll
            for (int p = 0; p < 2; ++p)
                #pragma unroll
                for (int c = 0; c < 3; ++c)
                    bnx[p][c] = *(const short8*)&WbT[(size_t)((ct0 + c) * 16 + l16) * 1024
                                                     + kn + p * 32 + quad * 8];
        }

        // convert current x to bf16 A-frags in-register
        short8 afr[2][2];
        #pragma unroll
        for (int mt = 0; mt < 2; ++mt)
            #pragma unroll
            for (int p = 0; p < 2; ++p) {
                const float4 a = xc[mt * 2 + p][0];
                const float4 b = xc[mt * 2 + p][1];
                union { unsigned int u[4]; short8 s; } cv;
                cv.u[0] = f2bf2(a.x, a.y); cv.u[1] = f2bf2(a.z, a.w);
                cv.u[2] = f2bf2(b.x, b.y); cv.u[3] = f2bf2(b.z, b.w);
                afr[mt][p] = cv.s;
            }

        __builtin_amdgcn_s_setprio(1);
        #pragma unroll
        for (int p = 0; p < 2; ++p)
            #pragma unroll
            for (int c = 0; c < 3; ++c) {
                acc[0][c] = __builtin_amdgcn_mfma_f32_16x16x32_bf16(afr[0][p], bfr[p][c], acc[0][c], 0, 0, 0);
                acc[1][c] = __builtin_amdgcn_mfma_f32_16x16x32_bf16(afr[1][p], bfr[p][c], acc[1][c], 0, 0, 0);
            }
        __builtin_amdgcn_s_setprio(0);

        #pragma unroll
        for (int i = 0; i < 4; ++i) { xc[i][0] = xn[i][0]; xc[i][1] = xn[i][1]; }
        #pragma unroll
        for (int p = 0; p < 2; ++p)
            #pragma unroll
            for (int c = 0; c < 3; ++c) bfr[p][c] = bnx[p][c];
    }

    // ---- epilogue (unchanged) ----
    const int half = (row0 >> 5) & 1;              // which 32-row half of the 64-tile
    const size_t tile = (size_t)(row0 >> 6) * 4096;
    #pragma unroll
    for (int c = 0; c < 3; ++c) {
        const int ct    = ct0 + c;
        const int mtype = ct >> 2;
        const int n0    = (ct & 3) * 16;
        #pragma unroll
        for (int mt = 0; mt < 2; ++mt) {
            const int row = row0 + mt * 16 + quad * 4;
            if (mtype == 0) {                       // q: row-major, /8 folded
                #pragma unroll
                for (int reg = 0; reg < 4; ++reg)
                    qb[(size_t)(row + reg) * HH + n0 + l16] = f2bf(acc[mt][c][reg] * 0.125f);
            } else if (mtype == 1) {                // K swizzled (B-frag order)
                const int cP    = half * 2 + mt;
                const int pP    = (ct & 3) >> 1;
                const int quadP = ((ct & 3) * 2 + (l16 >> 3)) & 3;
                const int jP    = l16 & 7;
                const int ub    = (cP * 2 + pP) * 64 + quadP * 16;
                #pragma unroll
                for (int reg = 0; reg < 4; ++reg)
                    kbS[tile + (size_t)(ub + quad * 4 + reg) * 8 + jP] = f2bf(acc[mt][c][reg]);
            } else {                                // V swizzled (B-frag order)
                const int cp2 = (ct & 3) * 2 + half;   // c'*2 + p'
                #pragma unroll
                for (int reg = 0; reg < 4; ++reg) {
                    const int rq    = quad * 4 + reg;
                    const int quadP = mt * 2 + (rq >> 3);
                    vS[tile + (size_t)(cp2 * 64 + quadP * 16 + l16) * 8 + (rq & 7)] = f2bf(acc[mt][c][reg]);
                }
            }
        }
    }
}

// ---------------------------------------------------------------------------
// Kernel 2: split-K MFMA flash attention (barrier-free, swapped QK^T).
// This round: V frags loaded after QK^T (liveness), Opart written
// TRANSPOSED+packed: [col][row] so each lane's 4 acc values are contiguous
// -> 2 cvt_pk + 1 b64 store per c (was 4 scalar f2bf+b16 stores).
// ---------------------------------------------------------------------------
__global__ __launch_bounds__(256) void attn_kernel(
    const ushort* __restrict__ qb, const ushort* __restrict__ kbS,
    const ushort* __restrict__ vS, ushort* __restrict__ Opart,
    float* __restrict__ ml)
{
    __shared__ __align__(16) ushort P[4][16 * 72];   // per-wave P tile

    const int t    = threadIdx.x;
    const int w    = t >> 6;
    const int lane = t & 63;
    const int l16  = lane & 15;
    const int quad = lane >> 4;

    const int b   = blockIdx.x & 7;
    const int idx = blockIdx.x >> 3;   // 0..79, heavy-first
    int qt, part, np;
    if (idx < 32)      { qt = 31 - (idx >> 2); part = idx & 3; np = 4; }
    else if (idx < 56) { const int u = idx - 32; const int g = u / 3;
                         qt = 23 - g; part = u - g * 3; np = 3; }
    else if (idx < 72) { const int u = idx - 56; qt = 15 - (u >> 1); part = u & 1; np = 2; }
    else               { qt = 7 - (idx - 72); part = 0; np = 1; }
    const int ntiles = qt + 1;
    const int ktb = (part * ntiles) / np;
    const int kte = ((part + 1) * ntiles) / np;

    const ushort* ktile0 = kbS + (size_t)(b * 32) * 4096;
    const ushort* vtile0 = vS  + (size_t)(b * 32) * 4096;

    // Q frags (B-operand of swapped QK^T; B-frag lane map == A-frag map)
    short8 qf[2];
    {
        const ushort* qrow = qb + ((size_t)b * TT + qt * 64 + w * 16) * HH;
        qf[0] = *(const short8*)&qrow[l16 * HH + quad * 8];
        qf[1] = *(const short8*)&qrow[l16 * HH + 32 + quad * 8];
    }
    short8 ones;
    #pragma unroll
    for (int i = 0; i < 8; ++i) ones[i] = (short)0x3F80;   // bf16 1.0

    floatx4 o[4], osum;
    #pragma unroll
    for (int c = 0; c < 4; ++c) o[c] = (floatx4){0.f, 0.f, 0.f, 0.f};
    osum = (floatx4){0.f, 0.f, 0.f, 0.f};

    ushort* Pw = &P[w][0];

    for (int kt = ktb; kt < kte; ++kt) {
        const ushort* kg = ktile0 + (size_t)kt * 4096;
        const ushort* vg = vtile0 + (size_t)kt * 4096;

        // ---- K frags from global (L2-hit, frag-ordered) ----
        short8 kf[4][2];
        #pragma unroll
        for (int c = 0; c < 4; ++c)
            #pragma unroll
            for (int p = 0; p < 2; ++p)
                kf[c][p] = *(const short8*)&kg[(size_t)(((c * 2 + p) * 64) + lane) * 8];

        // ---- S^T = K Q^T (operand-swapped): row=key chunk, col=q ----
        floatx4 s[4];
        #pragma unroll
        for (int c = 0; c < 4; ++c) s[c] = (floatx4){0.f, 0.f, 0.f, 0.f};
        __builtin_amdgcn_s_setprio(1);
        #pragma unroll
        for (int c = 0; c < 4; ++c)
            #pragma unroll
            for (int p = 0; p < 2; ++p)
                s[c] = __builtin_amdgcn_mfma_f32_16x16x32_bf16(kf[c][p], qf[p], s[c], 0, 0, 0);
        __builtin_amdgcn_s_setprio(0);

        // ---- V frags (issued while exp/P path runs) ----
        short8 vf[4][2];
        #pragma unroll
        for (int c = 0; c < 4; ++c)
            #pragma unroll
            for (int p = 0; p < 2; ++p)
                vf[c][p] = *(const short8*)&vg[(size_t)(((c * 2 + p) * 64) + lane) * 8];

        // ---- causal mask (roles swapped: key from reg, q from l16) ----
        if (kt == ntiles - 1) {
            const int key0 = kt * 64 + quad * 4;
            const int qrow = qt * 64 + w * 16 + l16;
            #pragma unroll
            for (int c = 0; c < 4; ++c)
                #pragma unroll
                for (int reg = 0; reg < 4; ++reg)
                    if (key0 + c * 16 + reg > qrow) s[c][reg] = -1e30f;
        }

        // ---- P = exp(s^T) -> packed bf16 -> LDS row q=l16, keys contiguous ----
        #pragma unroll
        for (int c = 0; c < 4; ++c) {
            uint2 u;
            u.x = f2bf2(__expf(s[c][0]), __expf(s[c][1]));
            u.y = f2bf2(__expf(s[c][2]), __expf(s[c][3]));
            *(uint2*)&Pw[l16 * 72 + c * 16 + quad * 4] = u;
        }

        short8 pf[2];
        pf[0] = *(const short8*)&Pw[l16 * 72 + quad * 8];
        pf[1] = *(const short8*)&Pw[l16 * 72 + 32 + quad * 8];

        // ---- O += P V ; l += P * ones ----
        __builtin_amdgcn_s_setprio(1);
        #pragma unroll
        for (int p = 0; p < 2; ++p) {
            #pragma unroll
            for (int c = 0; c < 4; ++c)
                o[c] = __builtin_amdgcn_mfma_f32_16x16x32_bf16(pf[p], vf[c][p], o[c], 0, 0, 0);
            osum = __builtin_amdgcn_mfma_f32_16x16x32_bf16(pf[p], ones, osum, 0, 0, 0);
        }
        __builtin_amdgcn_s_setprio(0);
    }

    // ---- write partial TRANSPOSED: Opart[unit][col][row], packed b64 ----
    const size_t ub = (size_t)blockIdx.x * 4096;
    const int rbase = w * 16 + quad * 4;
    #pragma unroll
    for (int c = 0; c < 4; ++c) {
        uint2 u;
        u.x = f2bf2(o[c][0], o[c][1]);
        u.y = f2bf2(o[c][2], o[c][3]);
        *(uint2*)&Opart[ub + (size_t)(c * 16 + l16) * 64 + rbase] = u;
    }
    if (l16 == 0) {
        #pragma unroll
        for (int reg = 0; reg < 4; ++reg)
            ml[(size_t)blockIdx.x * 64 + rbase + reg] = osum[reg];
    }
}

// ---------------------------------------------------------------------------
// Kernel 3: merge partials (transposed Opart).  out = (sum O_p) / (sum l_p).
// lane = col; 4 consecutive rows per ushort4 load; float4 ml loads.
// ---------------------------------------------------------------------------
__global__ __launch_bounds__(256) void merge_kernel(
    const ushort* __restrict__ Opart, const float* __restrict__ ml,
    float* __restrict__ out)
{
    const int t    = threadIdx.x;
    const int gw   = blockIdx.x * 4 + (t >> 6);   // 0..2047
    const int lane = t & 63;                      // = output col
    const int b    = gw >> 8;
    const int v    = gw & 255;
    const int qt   = v >> 3;
    const int oct  = v & 7;

    int base, np;
    if (qt >= 24)      { base = (31 - qt) * 4;      np = 4; }
    else if (qt >= 16) { base = 32 + (23 - qt) * 3; np = 3; }
    else if (qt >= 8)  { base = 56 + (15 - qt) * 2; np = 2; }
    else               { base = 72 + (7 - qt);      np = 1; }

    float* obase = out + ((size_t)b * TT + qt * 64) * HH;

    #pragma unroll
    for (int rg = 0; rg < 2; ++rg) {
        const int row0 = oct * 8 + rg * 4;
        float dx = 0.f, dy = 0.f, dz = 0.f, dw = 0.f;
        float ax = 0.f, ay = 0.f, az = 0.f, aw = 0.f;
        for (int p = 0; p < np; ++p) {
            const int unit = (base + p) * 8 + b;
            float4 d = *(const float4*)&ml[(size_t)unit * 64 + row0];
            dx += d.x; dy += d.y; dz += d.z; dw += d.w;
            ushort4 ov = *(const ushort4*)&Opart[(size_t)unit * 4096 + lane * 64 + row0];
            ax += bf2f(ov.x); ay += bf2f(ov.y); az += bf2f(ov.z); aw += bf2f(ov.w);
        }
        obase[(size_t)(row0 + 0) * HH + lane] = ax / dx;
        obase[(size_t)(row0 + 1) * HH + lane] = ay / dy;
        obase[(size_t)(row0 + 2) * HH + lane] = az / dz;
        obase[(size_t)(row0 + 3) * HH + lane] = aw / dw;
    }
}

// ---------------------------------------------------------------------------
extern "C" void kernel_launch(void* const* d_in, const int* in_sizes, int n_in,
                              void* d_out, int out_size, void* d_ws, size_t ws_size,
                              hipStream_t stream)
{
    (void)in_sizes; (void)n_in; (void)out_size; (void)ws_size;
    const float* x  = (const float*)d_in[0];
    const float* Wq = (const float*)d_in[1];
    const float* Wk = (const float*)d_in[2];
    const float* Wv = (const float*)d_in[3];
    float* outp = (float*)d_out;

    // ws: WbT 384K | qb 2M | kbS 2M | vS 2M | Opart 5.24M | ml 160K (~11.8 MB)
    char* base = (char*)d_ws;
    ushort* WbT   = (ushort*)(base);
    ushort* qbuf  = (ushort*)(base + 393216);
    ushort* kbS   = qbuf + (size_t)BT * HH;
    ushort* vSb   = kbS + (size_t)BT * HH;
    ushort* Opart = vSb + (size_t)BT * HH;
    float*  ml    = (float*)((char*)Opart + (size_t)640 * 4096 * 2);

    wprep_kernel<<<dim3(48),  256, 0, stream>>>(Wq, Wk, Wv, WbT);
    qkv_kernel  <<<dim3(512), 256, 0, stream>>>(x, WbT, qbuf, kbS, vSb);
    attn_kernel <<<dim3(640), 256, 0, stream>>>(qbuf, kbS, vSb, Opart, ml);
    merge_kernel<<<dim3(512), 256, 0, stream>>>(Opart, ml, outp);
}

// Round 4
// 154.498 us; speedup vs baseline: 1.0265x; 1.0265x over previous
//
#include <hip/hip_runtime.h>
#include <hip/hip_bf16.h>
#include <math.h>

#define BB 8
#define TT 2048
#define CC 1024
#define HH 64
#define BT (BB * TT)   // 16384 rows

typedef __attribute__((ext_vector_type(8))) short short8;   // bf16 x8 MFMA frag
typedef __attribute__((ext_vector_type(4))) float floatx4;  // MFMA acc

static __device__ inline ushort f2bf(float f) {
    __hip_bfloat16 h = __float2bfloat16(f);
    return *reinterpret_cast<ushort*>(&h);
}
static __device__ inline unsigned int f2bf2(float lo, float hi) {
    __hip_bfloat162 h = __float22bfloat162_rn(make_float2(lo, hi));
    return *reinterpret_cast<unsigned int*>(&h);
}
static __device__ inline float bf2f(ushort u) {
    union { unsigned int i; float f; } c;
    c.i = ((unsigned int)u) << 16;
    return c.f;
}

// ---------------------------------------------------------------------------
// Kernel 0: W prep (coalesced).  W[k][n] fp32 -> WbT[m][n][k] bf16.
// ---------------------------------------------------------------------------
__global__ __launch_bounds__(256) void wprep_kernel(
    const float* __restrict__ Wq, const float* __restrict__ Wk,
    const float* __restrict__ Wv, ushort* __restrict__ WbT)
{
    __shared__ float ws_[64 * 65];
    const int m  = blockIdx.x >> 4;          // 0..2
    const int kb = (blockIdx.x & 15) * 64;   // 0..960
    const float* W = (m == 0) ? Wq : (m == 1) ? Wk : Wv;
    const int t  = threadIdx.x;
    const int lr = t >> 4, lc = (t & 15) * 4;
    #pragma unroll
    for (int i = 0; i < 4; ++i) {
        const int row = lr + i * 16;
        float4 v = *(const float4*)&W[(size_t)(kb + row) * HH + lc];
        ws_[row * 65 + lc + 0] = v.x; ws_[row * 65 + lc + 1] = v.y;
        ws_[row * 65 + lc + 2] = v.z; ws_[row * 65 + lc + 3] = v.w;
    }
    __syncthreads();
    const int n = t & 63, kseg = t >> 6;     // kseg 0..3 -> 16 k each
    union { ushort s[16]; uint4 q[2]; } u;
    #pragma unroll
    for (int j = 0; j < 16; ++j)
        u.s[j] = f2bf(ws_[(kseg * 16 + j) * 65 + n]);
    ushort* dst = &WbT[(size_t)(m * 64 + n) * 1024 + kb + kseg * 16];
    *(uint4*)&dst[0] = u.q[0];
    *(uint4*)&dst[8] = u.q[1];
}

// ---------------------------------------------------------------------------
// Kernel 1: QKV via bf16 MFMA — staged-LDS again (round-3's direct-global
// version was latency-bound at 58 µs), but restructured for occupancy:
//  - 16-row blocks, grid 1024 -> 4 blocks/CU: barrier drains of one block
//    overlap compute of the other three (m114 wave-level overlap).
//  - staging: thread (srow=t>>4, sseg=t&15) loads one float4 -> 16 lanes
//    cover one row's 256 B contiguous (fully coalesced).
//  - LDS tile is bf16 frag-major with XOR swizzle byte^=(row&7)<<4:
//    conflict-free b128 reads AND floor-rate b64 writes (verified on paper).
// ---------------------------------------------------------------------------
__global__ __launch_bounds__(256) void qkv_kernel(
    const float* __restrict__ x, const ushort* __restrict__ WbT,
    ushort* __restrict__ qb, ushort* __restrict__ kbS, ushort* __restrict__ vS)
{
    __shared__ __align__(16) ushort As[2][1024];   // 2 KB per buffer

    const int row0 = blockIdx.x * 16;
    const int t    = threadIdx.x;
    const int w    = t >> 6;
    const int lane = t & 63;
    const int l16  = lane & 15;
    const int quad = lane >> 4;
    const int ct0  = w * 3;

    // ---- staging thread map: srow = row, sseg*4 = k offset within 64 ----
    const int srow = t >> 4, sseg = t & 15;
    const int sp = sseg >> 3, squad = (sseg >> 1) & 3, shalf = sseg & 1;
    const int widx = (((sp * 64 + srow * 4 + squad) * 8) + shalf * 4)
                     ^ ((srow & 7) << 3);                    // ushort index
    const float* xsrc = &x[(size_t)(row0 + srow) * CC + sseg * 4];

    // ---- compute-side read offsets (swizzled, b128) ----
    const int ridx0 = ((l16 * 4 + quad) * 8)       ^ ((l16 & 7) << 3);
    const int ridx1 = ((64 + l16 * 4 + quad) * 8)  ^ ((l16 & 7) << 3);

    floatx4 acc[3];
    #pragma unroll
    for (int c = 0; c < 3; ++c) acc[c] = (floatx4){0.f, 0.f, 0.f, 0.f};

    float4 xc = *(const float4*)&xsrc[0];
    float4 xn;

    short8 bfr[2][3], bnx[2][3];
    #pragma unroll
    for (int p = 0; p < 2; ++p)
        #pragma unroll
        for (int c = 0; c < 3; ++c)
            bfr[p][c] = *(const short8*)&WbT[(size_t)((ct0 + c) * 16 + l16) * 1024
                                             + p * 32 + quad * 8];

    for (int it = 0; it < 16; ++it) {
        uint2 uq;
        uq.x = f2bf2(xc.x, xc.y);
        uq.y = f2bf2(xc.z, xc.w);
        *(uint2*)&As[it & 1][widx] = uq;
        __syncthreads();

        if (it < 15) {
            xn = *(const float4*)&xsrc[(it + 1) * 64];
            const int kn = (it + 1) * 64;
            #pragma unroll
            for (int p = 0; p < 2; ++p)
                #pragma unroll
                for (int c = 0; c < 3; ++c)
                    bnx[p][c] = *(const short8*)&WbT[(size_t)((ct0 + c) * 16 + l16) * 1024
                                                     + kn + p * 32 + quad * 8];
        }

        short8 a0 = *(const short8*)&As[it & 1][ridx0];
        short8 a1 = *(const short8*)&As[it & 1][ridx1];

        __builtin_amdgcn_s_setprio(1);
        #pragma unroll
        for (int c = 0; c < 3; ++c) {
            acc[c] = __builtin_amdgcn_mfma_f32_16x16x32_bf16(a0, bfr[0][c], acc[c], 0, 0, 0);
            acc[c] = __builtin_amdgcn_mfma_f32_16x16x32_bf16(a1, bfr[1][c], acc[c], 0, 0, 0);
        }
        __builtin_amdgcn_s_setprio(0);

        xc = xn;
        #pragma unroll
        for (int p = 0; p < 2; ++p)
            #pragma unroll
            for (int c = 0; c < 3; ++c) bfr[p][c] = bnx[p][c];
    }

    // ---- epilogue (16-row block: mt/half derived from row0) ----
    const int half = (row0 >> 5) & 1;     // which 32-row half of the 64-tile
    const int mt   = (row0 >> 4) & 1;     // which 16-row sub-tile of the 32
    const size_t tile = (size_t)(row0 >> 6) * 4096;
    #pragma unroll
    for (int c = 0; c < 3; ++c) {
        const int ct    = ct0 + c;
        const int mtype = ct >> 2;
        const int n0    = (ct & 3) * 16;
        const int row   = row0 + quad * 4;
        if (mtype == 0) {                       // q: row-major, /8 folded
            #pragma unroll
            for (int reg = 0; reg < 4; ++reg)
                qb[(size_t)(row + reg) * HH + n0 + l16] = f2bf(acc[c][reg] * 0.125f);
        } else if (mtype == 1) {                // K swizzled (B-frag order)
            const int cP    = half * 2 + mt;
            const int pP    = (ct & 3) >> 1;
            const int quadP = ((ct & 3) * 2 + (l16 >> 3)) & 3;
            const int jP    = l16 & 7;
            const int ub    = (cP * 2 + pP) * 64 + quadP * 16;
            #pragma unroll
            for (int reg = 0; reg < 4; ++reg)
                kbS[tile + (size_t)(ub + quad * 4 + reg) * 8 + jP] = f2bf(acc[c][reg]);
        } else {                                // V swizzled (B-frag order)
            const int cp2 = (ct & 3) * 2 + half;   // c'*2 + p'
            #pragma unroll
            for (int reg = 0; reg < 4; ++reg) {
                const int rq    = quad * 4 + reg;
                const int quadP = mt * 2 + (rq >> 3);
                vS[tile + (size_t)(cp2 * 64 + quadP * 16 + l16) * 8 + (rq & 7)] = f2bf(acc[c][reg]);
            }
        }
    }
}

// ---------------------------------------------------------------------------
// Kernel 2: split-K MFMA flash attention (barrier-free, swapped QK^T,
// transposed packed Opart).  Unchanged from round 3.
// ---------------------------------------------------------------------------
__global__ __launch_bounds__(256) void attn_kernel(
    const ushort* __restrict__ qb, const ushort* __restrict__ kbS,
    const ushort* __restrict__ vS, ushort* __restrict__ Opart,
    float* __restrict__ ml)
{
    __shared__ __align__(16) ushort P[4][16 * 72];   // per-wave P tile

    const int t    = threadIdx.x;
    const int w    = t >> 6;
    const int lane = t & 63;
    const int l16  = lane & 15;
    const int quad = lane >> 4;

    const int b   = blockIdx.x & 7;
    const int idx = blockIdx.x >> 3;   // 0..79, heavy-first
    int qt, part, np;
    if (idx < 32)      { qt = 31 - (idx >> 2); part = idx & 3; np = 4; }
    else if (idx < 56) { const int u = idx - 32; const int g = u / 3;
                         qt = 23 - g; part = u - g * 3; np = 3; }
    else if (idx < 72) { const int u = idx - 56; qt = 15 - (u >> 1); part = u & 1; np = 2; }
    else               { qt = 7 - (idx - 72); part = 0; np = 1; }
    const int ntiles = qt + 1;
    const int ktb = (part * ntiles) / np;
    const int kte = ((part + 1) * ntiles) / np;

    const ushort* ktile0 = kbS + (size_t)(b * 32) * 4096;
    const ushort* vtile0 = vS  + (size_t)(b * 32) * 4096;

    // Q frags (B-operand of swapped QK^T; B-frag lane map == A-frag map)
    short8 qf[2];
    {
        const ushort* qrow = qb + ((size_t)b * TT + qt * 64 + w * 16) * HH;
        qf[0] = *(const short8*)&qrow[l16 * HH + quad * 8];
        qf[1] = *(const short8*)&qrow[l16 * HH + 32 + quad * 8];
    }
    short8 ones;
    #pragma unroll
    for (int i = 0; i < 8; ++i) ones[i] = (short)0x3F80;   // bf16 1.0

    floatx4 o[4], osum;
    #pragma unroll
    for (int c = 0; c < 4; ++c) o[c] = (floatx4){0.f, 0.f, 0.f, 0.f};
    osum = (floatx4){0.f, 0.f, 0.f, 0.f};

    ushort* Pw = &P[w][0];

    for (int kt = ktb; kt < kte; ++kt) {
        const ushort* kg = ktile0 + (size_t)kt * 4096;
        const ushort* vg = vtile0 + (size_t)kt * 4096;

        // ---- K frags from global (L2-hit, frag-ordered) ----
        short8 kf[4][2];
        #pragma unroll
        for (int c = 0; c < 4; ++c)
            #pragma unroll
            for (int p = 0; p < 2; ++p)
                kf[c][p] = *(const short8*)&kg[(size_t)(((c * 2 + p) * 64) + lane) * 8];

        // ---- S^T = K Q^T (operand-swapped): row=key chunk, col=q ----
        floatx4 s[4];
        #pragma unroll
        for (int c = 0; c < 4; ++c) s[c] = (floatx4){0.f, 0.f, 0.f, 0.f};
        __builtin_amdgcn_s_setprio(1);
        #pragma unroll
        for (int c = 0; c < 4; ++c)
            #pragma unroll
            for (int p = 0; p < 2; ++p)
                s[c] = __builtin_amdgcn_mfma_f32_16x16x32_bf16(kf[c][p], qf[p], s[c], 0, 0, 0);
        __builtin_amdgcn_s_setprio(0);

        // ---- V frags (issued while exp/P path runs) ----
        short8 vf[4][2];
        #pragma unroll
        for (int c = 0; c < 4; ++c)
            #pragma unroll
            for (int p = 0; p < 2; ++p)
                vf[c][p] = *(const short8*)&vg[(size_t)(((c * 2 + p) * 64) + lane) * 8];

        // ---- causal mask (roles swapped: key from reg, q from l16) ----
        if (kt == ntiles - 1) {
            const int key0 = kt * 64 + quad * 4;
            const int qrow = qt * 64 + w * 16 + l16;
            #pragma unroll
            for (int c = 0; c < 4; ++c)
                #pragma unroll
                for (int reg = 0; reg < 4; ++reg)
                    if (key0 + c * 16 + reg > qrow) s[c][reg] = -1e30f;
        }

        // ---- P = exp(s^T) -> packed bf16 -> LDS row q=l16, keys contiguous ----
        #pragma unroll
        for (int c = 0; c < 4; ++c) {
            uint2 u;
            u.x = f2bf2(__expf(s[c][0]), __expf(s[c][1]));
            u.y = f2bf2(__expf(s[c][2]), __expf(s[c][3]));
            *(uint2*)&Pw[l16 * 72 + c * 16 + quad * 4] = u;
        }

        short8 pf[2];
        pf[0] = *(const short8*)&Pw[l16 * 72 + quad * 8];
        pf[1] = *(const short8*)&Pw[l16 * 72 + 32 + quad * 8];

        // ---- O += P V ; l += P * ones ----
        __builtin_amdgcn_s_setprio(1);
        #pragma unroll
        for (int p = 0; p < 2; ++p) {
            #pragma unroll
            for (int c = 0; c < 4; ++c)
                o[c] = __builtin_amdgcn_mfma_f32_16x16x32_bf16(pf[p], vf[c][p], o[c], 0, 0, 0);
            osum = __builtin_amdgcn_mfma_f32_16x16x32_bf16(pf[p], ones, osum, 0, 0, 0);
        }
        __builtin_amdgcn_s_setprio(0);
    }

    // ---- write partial TRANSPOSED: Opart[unit][col][row], packed b64 ----
    const size_t ub = (size_t)blockIdx.x * 4096;
    const int rbase = w * 16 + quad * 4;
    #pragma unroll
    for (int c = 0; c < 4; ++c) {
        uint2 u;
        u.x = f2bf2(o[c][0], o[c][1]);
        u.y = f2bf2(o[c][2], o[c][3]);
        *(uint2*)&Opart[ub + (size_t)(c * 16 + l16) * 64 + rbase] = u;
    }
    if (l16 == 0) {
        #pragma unroll
        for (int reg = 0; reg < 4; ++reg)
            ml[(size_t)blockIdx.x * 64 + rbase + reg] = osum[reg];
    }
}

// ---------------------------------------------------------------------------
// Kernel 3: merge partials (transposed Opart).  out = (sum O_p) / (sum l_p).
// ---------------------------------------------------------------------------
__global__ __launch_bounds__(256) void merge_kernel(
    const ushort* __restrict__ Opart, const float* __restrict__ ml,
    float* __restrict__ out)
{
    const int t    = threadIdx.x;
    const int gw   = blockIdx.x * 4 + (t >> 6);   // 0..2047
    const int lane = t & 63;                      // = output col
    const int b    = gw >> 8;
    const int v    = gw & 255;
    const int qt   = v >> 3;
    const int oct  = v & 7;

    int base, np;
    if (qt >= 24)      { base = (31 - qt) * 4;      np = 4; }
    else if (qt >= 16) { base = 32 + (23 - qt) * 3; np = 3; }
    else if (qt >= 8)  { base = 56 + (15 - qt) * 2; np = 2; }
    else               { base = 72 + (7 - qt);      np = 1; }

    float* obase = out + ((size_t)b * TT + qt * 64) * HH;

    #pragma unroll
    for (int rg = 0; rg < 2; ++rg) {
        const int row0 = oct * 8 + rg * 4;
        float dx = 0.f, dy = 0.f, dz = 0.f, dw = 0.f;
        float ax = 0.f, ay = 0.f, az = 0.f, aw = 0.f;
        for (int p = 0; p < np; ++p) {
            const int unit = (base + p) * 8 + b;
            float4 d = *(const float4*)&ml[(size_t)unit * 64 + row0];
            dx += d.x; dy += d.y; dz += d.z; dw += d.w;
            ushort4 ov = *(const ushort4*)&Opart[(size_t)unit * 4096 + lane * 64 + row0];
            ax += bf2f(ov.x); ay += bf2f(ov.y); az += bf2f(ov.z); aw += bf2f(ov.w);
        }
        obase[(size_t)(row0 + 0) * HH + lane] = ax / dx;
        obase[(size_t)(row0 + 1) * HH + lane] = ay / dy;
        obase[(size_t)(row0 + 2) * HH + lane] = az / dz;
        obase[(size_t)(row0 + 3) * HH + lane] = aw / dw;
    }
}

// ---------------------------------------------------------------------------
extern "C" void kernel_launch(void* const* d_in, const int* in_sizes, int n_in,
                              void* d_out, int out_size, void* d_ws, size_t ws_size,
                              hipStream_t stream)
{
    (void)in_sizes; (void)n_in; (void)out_size; (void)ws_size;
    const float* x  = (const float*)d_in[0];
    const float* Wq = (const float*)d_in[1];
    const float* Wk = (const float*)d_in[2];
    const float* Wv = (const float*)d_in[3];
    float* outp = (float*)d_out;

    // ws: WbT 384K | qb 2M | kbS 2M | vS 2M | Opart 5.24M | ml 160K (~11.8 MB)
    char* base = (char*)d_ws;
    ushort* WbT   = (ushort*)(base);
    ushort* qbuf  = (ushort*)(base + 393216);
    ushort* kbS   = qbuf + (size_t)BT * HH;
    ushort* vSb   = kbS + (size_t)BT * HH;
    ushort* Opart = vSb + (size_t)BT * HH;
    float*  ml    = (float*)((char*)Opart + (size_t)640 * 4096 * 2);

    wprep_kernel<<<dim3(48),   256, 0, stream>>>(Wq, Wk, Wv, WbT);
    qkv_kernel  <<<dim3(1024), 256, 0, stream>>>(x, WbT, qbuf, kbS, vSb);
    attn_kernel <<<dim3(640),  256, 0, stream>>>(qbuf, kbS, vSb, Opart, ml);
    merge_kernel<<<dim3(512),  256, 0, stream>>>(Opart, ml, outp);
}

// Round 5
// 138.200 us; speedup vs baseline: 1.1476x; 1.1179x over previous
//
#include <hip/hip_runtime.h>
#include <hip/hip_bf16.h>
#include <math.h>

#define BB 8
#define TT 2048
#define CC 1024
#define HH 64
#define BT (BB * TT)   // 16384 rows

typedef __attribute__((ext_vector_type(8))) short short8;   // bf16 x8 MFMA frag
typedef __attribute__((ext_vector_type(4))) float floatx4;  // MFMA acc

static __device__ inline ushort f2bf(float f) {
    __hip_bfloat16 h = __float2bfloat16(f);
    return *reinterpret_cast<ushort*>(&h);
}
static __device__ inline unsigned int f2bf2(float lo, float hi) {
    __hip_bfloat162 h = __float22bfloat162_rn(make_float2(lo, hi));
    return *reinterpret_cast<unsigned int*>(&h);
}
static __device__ inline float bf2f(ushort u) {
    union { unsigned int i; float f; } c;
    c.i = ((unsigned int)u) << 16;
    return c.f;
}
// Barrier that waits ONLY on LDS ops: VMEM prefetches (x, WbT) stay in
// flight across it (T4 counted-wait principle; __syncthreads would drain
// vmcnt(0) and throw the pipeline away every iteration).
static __device__ inline void lds_barrier() {
    asm volatile("s_waitcnt lgkmcnt(0)" ::: "memory");
    __builtin_amdgcn_s_barrier();
}

// ---------------------------------------------------------------------------
// Kernel 0: W prep (coalesced).  W[k][n] fp32 -> WbT[m][n][k] bf16.
// ---------------------------------------------------------------------------
__global__ __launch_bounds__(256) void wprep_kernel(
    const float* __restrict__ Wq, const float* __restrict__ Wk,
    const float* __restrict__ Wv, ushort* __restrict__ WbT)
{
    __shared__ float ws_[64 * 65];
    const int m  = blockIdx.x >> 4;          // 0..2
    const int kb = (blockIdx.x & 15) * 64;   // 0..960
    const float* W = (m == 0) ? Wq : (m == 1) ? Wk : Wv;
    const int t  = threadIdx.x;
    const int lr = t >> 4, lc = (t & 15) * 4;
    #pragma unroll
    for (int i = 0; i < 4; ++i) {
        const int row = lr + i * 16;
        float4 v = *(const float4*)&W[(size_t)(kb + row) * HH + lc];
        ws_[row * 65 + lc + 0] = v.x; ws_[row * 65 + lc + 1] = v.y;
        ws_[row * 65 + lc + 2] = v.z; ws_[row * 65 + lc + 3] = v.w;
    }
    __syncthreads();
    const int n = t & 63, kseg = t >> 6;     // kseg 0..3 -> 16 k each
    union { ushort s[16]; uint4 q[2]; } u;
    #pragma unroll
    for (int j = 0; j < 16; ++j)
        u.s[j] = f2bf(ws_[(kseg * 16 + j) * 65 + n]);
    ushort* dst = &WbT[(size_t)(m * 64 + n) * 1024 + kb + kseg * 16];
    *(uint4*)&dst[0] = u.q[0];
    *(uint4*)&dst[8] = u.q[1];
}

// ---------------------------------------------------------------------------
// Kernel 1: QKV via bf16 MFMA — round-0 32-row staged structure, but the
// per-iter barrier waits lgkmcnt ONLY (raw s_barrier): x depth-2 prefetch
// and WbT depth-1 prefetch now SURVIVE the barrier instead of being drained
// by __syncthreads' vmcnt(0).  Staging write & frag reads are both at the
// ideal 8-lanes-per-4-bank-group depth (checked by hand).
// ---------------------------------------------------------------------------
__global__ __launch_bounds__(256) void qkv_kernel(
    const float* __restrict__ x, const ushort* __restrict__ WbT,
    ushort* __restrict__ qb, ushort* __restrict__ kbS, ushort* __restrict__ vS)
{
    __shared__ __align__(16) ushort As[2][256 * 8];   // frag-major

    const int row0 = blockIdx.x * 32;
    const int t    = threadIdx.x;
    const int w    = t >> 6;
    const int lane = t & 63;
    const int l16  = lane & 15;
    const int quad = lane >> 4;
    const int ct0  = w * 3;

    const int srow = t >> 3, sseg = t & 7;
    const int slot = (((sseg >> 2) * 2 + (srow >> 4)) * 16 + (srow & 15)) * 4 + (sseg & 3);
    const float* xsrc = &x[(size_t)(row0 + srow) * CC + sseg * 8];

    floatx4 acc[2][3];
    #pragma unroll
    for (int mt = 0; mt < 2; ++mt)
        #pragma unroll
        for (int c = 0; c < 3; ++c) acc[mt][c] = (floatx4){0.f, 0.f, 0.f, 0.f};

    // ---- depth-2 register prefetch of x ----
    float4 xa0 = *(const float4*)&xsrc[0];
    float4 xb0 = *(const float4*)&xsrc[4];
    float4 xa1 = *(const float4*)&xsrc[64];
    float4 xb1 = *(const float4*)&xsrc[68];

    short8 bfr[2][3];
    #pragma unroll
    for (int p = 0; p < 2; ++p)
        #pragma unroll
        for (int c = 0; c < 3; ++c)
            bfr[p][c] = *(const short8*)&WbT[(size_t)((ct0 + c) * 16 + l16) * 1024
                                             + p * 32 + quad * 8];

    auto body = [&](int it, float4& xa, float4& xb) {
        uint4 uq;
        uq.x = f2bf2(xa.x, xa.y); uq.y = f2bf2(xa.z, xa.w);
        uq.z = f2bf2(xb.x, xb.y); uq.w = f2bf2(xb.z, xb.w);
        *(uint4*)&As[it & 1][slot * 8] = uq;
        lds_barrier();                        // lgkm-only: VMEM stays in flight

        if (it + 2 < 16) {                    // x prefetch, 2 iters ahead
            xa = *(const float4*)&xsrc[(it + 2) * 64 + 0];
            xb = *(const float4*)&xsrc[(it + 2) * 64 + 4];
        }
        short8 bnx[2][3];
        if (it < 15) {                        // WbT prefetch, 1 iter ahead
            const int kn = (it + 1) * 64;
            #pragma unroll
            for (int p = 0; p < 2; ++p)
                #pragma unroll
                for (int c = 0; c < 3; ++c)
                    bnx[p][c] = *(const short8*)&WbT[(size_t)((ct0 + c) * 16 + l16) * 1024
                                                     + kn + p * 32 + quad * 8];
        }

        short8 a0 = *(const short8*)&As[it & 1][(size_t)((0 * 2 + 0) * 64 + l16 * 4 + quad) * 8 + 0];
        short8 a1 = *(const short8*)&As[it & 1][(size_t)((0 * 2 + 1) * 64 + l16 * 4 + quad) * 8 + 0];
        short8 a2 = *(const short8*)&As[it & 1][(size_t)((1 * 2 + 0) * 64 + l16 * 4 + quad) * 8 + 0];
        short8 a3 = *(const short8*)&As[it & 1][(size_t)((1 * 2 + 1) * 64 + l16 * 4 + quad) * 8 + 0];

        __builtin_amdgcn_s_setprio(1);
        #pragma unroll
        for (int c = 0; c < 3; ++c) {
            acc[0][c] = __builtin_amdgcn_mfma_f32_16x16x32_bf16(a0, bfr[0][c], acc[0][c], 0, 0, 0);
            acc[1][c] = __builtin_amdgcn_mfma_f32_16x16x32_bf16(a1, bfr[0][c], acc[1][c], 0, 0, 0);
            acc[0][c] = __builtin_amdgcn_mfma_f32_16x16x32_bf16(a2, bfr[1][c], acc[0][c], 0, 0, 0);
            acc[1][c] = __builtin_amdgcn_mfma_f32_16x16x32_bf16(a3, bfr[1][c], acc[1][c], 0, 0, 0);
        }
        __builtin_amdgcn_s_setprio(0);

        #pragma unroll
        for (int p = 0; p < 2; ++p)
            #pragma unroll
            for (int c = 0; c < 3; ++c)
                bfr[p][c] = bnx[p][c];
    };

    for (int it2 = 0; it2 < 16; it2 += 2) {
        body(it2 + 0, xa0, xb0);
        body(it2 + 1, xa1, xb1);
    }

    // ---- epilogue ----
    const int half = (row0 >> 5) & 1;              // which 32-row half of the 64-tile
    const size_t tile = (size_t)(row0 >> 6) * 4096;
    #pragma unroll
    for (int c = 0; c < 3; ++c) {
        const int ct    = ct0 + c;
        const int mtype = ct >> 2;
        const int n0    = (ct & 3) * 16;
        #pragma unroll
        for (int mt = 0; mt < 2; ++mt) {
            const int row = row0 + mt * 16 + quad * 4;
            if (mtype == 0) {                       // q: row-major, /8 folded
                #pragma unroll
                for (int reg = 0; reg < 4; ++reg)
                    qb[(size_t)(row + reg) * HH + n0 + l16] = f2bf(acc[mt][c][reg] * 0.125f);
            } else if (mtype == 1) {                // K swizzled (B-frag order)
                const int cP    = half * 2 + mt;
                const int pP    = (ct & 3) >> 1;
                const int quadP = ((ct & 3) * 2 + (l16 >> 3)) & 3;
                const int jP    = l16 & 7;
                const int ub    = (cP * 2 + pP) * 64 + quadP * 16;
                #pragma unroll
                for (int reg = 0; reg < 4; ++reg)
                    kbS[tile + (size_t)(ub + quad * 4 + reg) * 8 + jP] = f2bf(acc[mt][c][reg]);
            } else {                                // V swizzled (B-frag order)
                const int cp2 = (ct & 3) * 2 + half;   // c'*2 + p'
                #pragma unroll
                for (int reg = 0; reg < 4; ++reg) {
                    const int rq    = quad * 4 + reg;
                    const int quadP = mt * 2 + (rq >> 3);
                    vS[tile + (size_t)(cp2 * 64 + quadP * 16 + l16) * 8 + (rq & 7)] = f2bf(acc[mt][c][reg]);
                }
            }
        }
    }
}

// ---------------------------------------------------------------------------
// Kernel 2: split-K MFMA flash attention (barrier-free, swapped QK^T,
// transposed packed Opart).  Unchanged this round.
// ---------------------------------------------------------------------------
__global__ __launch_bounds__(256) void attn_kernel(
    const ushort* __restrict__ qb, const ushort* __restrict__ kbS,
    const ushort* __restrict__ vS, ushort* __restrict__ Opart,
    float* __restrict__ ml)
{
    __shared__ __align__(16) ushort P[4][16 * 72];   // per-wave P tile

    const int t    = threadIdx.x;
    const int w    = t >> 6;
    const int lane = t & 63;
    const int l16  = lane & 15;
    const int quad = lane >> 4;

    const int b   = blockIdx.x & 7;
    const int idx = blockIdx.x >> 3;   // 0..79, heavy-first
    int qt, part, np;
    if (idx < 32)      { qt = 31 - (idx >> 2); part = idx & 3; np = 4; }
    else if (idx < 56) { const int u = idx - 32; const int g = u / 3;
                         qt = 23 - g; part = u - g * 3; np = 3; }
    else if (idx < 72) { const int u = idx - 56; qt = 15 - (u >> 1); part = u & 1; np = 2; }
    else               { qt = 7 - (idx - 72); part = 0; np = 1; }
    const int ntiles = qt + 1;
    const int ktb = (part * ntiles) / np;
    const int kte = ((part + 1) * ntiles) / np;

    const ushort* ktile0 = kbS + (size_t)(b * 32) * 4096;
    const ushort* vtile0 = vS  + (size_t)(b * 32) * 4096;

    // Q frags (B-operand of swapped QK^T; B-frag lane map == A-frag map)
    short8 qf[2];
    {
        const ushort* qrow = qb + ((size_t)b * TT + qt * 64 + w * 16) * HH;
        qf[0] = *(const short8*)&qrow[l16 * HH + quad * 8];
        qf[1] = *(const short8*)&qrow[l16 * HH + 32 + quad * 8];
    }
    short8 ones;
    #pragma unroll
    for (int i = 0; i < 8; ++i) ones[i] = (short)0x3F80;   // bf16 1.0

    floatx4 o[4], osum;
    #pragma unroll
    for (int c = 0; c < 4; ++c) o[c] = (floatx4){0.f, 0.f, 0.f, 0.f};
    osum = (floatx4){0.f, 0.f, 0.f, 0.f};

    ushort* Pw = &P[w][0];

    for (int kt = ktb; kt < kte; ++kt) {
        const ushort* kg = ktile0 + (size_t)kt * 4096;
        const ushort* vg = vtile0 + (size_t)kt * 4096;

        // ---- K frags from global (L2-hit, frag-ordered) ----
        short8 kf[4][2];
        #pragma unroll
        for (int c = 0; c < 4; ++c)
            #pragma unroll
            for (int p = 0; p < 2; ++p)
                kf[c][p] = *(const short8*)&kg[(size_t)(((c * 2 + p) * 64) + lane) * 8];

        // ---- S^T = K Q^T (operand-swapped): row=key chunk, col=q ----
        floatx4 s[4];
        #pragma unroll
        for (int c = 0; c < 4; ++c) s[c] = (floatx4){0.f, 0.f, 0.f, 0.f};
        __builtin_amdgcn_s_setprio(1);
        #pragma unroll
        for (int c = 0; c < 4; ++c)
            #pragma unroll
            for (int p = 0; p < 2; ++p)
                s[c] = __builtin_amdgcn_mfma_f32_16x16x32_bf16(kf[c][p], qf[p], s[c], 0, 0, 0);
        __builtin_amdgcn_s_setprio(0);

        // ---- V frags (issued while exp/P path runs) ----
        short8 vf[4][2];
        #pragma unroll
        for (int c = 0; c < 4; ++c)
            #pragma unroll
            for (int p = 0; p < 2; ++p)
                vf[c][p] = *(const short8*)&vg[(size_t)(((c * 2 + p) * 64) + lane) * 8];

        // ---- causal mask (roles swapped: key from reg, q from l16) ----
        if (kt == ntiles - 1) {
            const int key0 = kt * 64 + quad * 4;
            const int qrow = qt * 64 + w * 16 + l16;
            #pragma unroll
            for (int c = 0; c < 4; ++c)
                #pragma unroll
                for (int reg = 0; reg < 4; ++reg)
                    if (key0 + c * 16 + reg > qrow) s[c][reg] = -1e30f;
        }

        // ---- P = exp(s^T) -> packed bf16 -> LDS row q=l16, keys contiguous ----
        #pragma unroll
        for (int c = 0; c < 4; ++c) {
            uint2 u;
            u.x = f2bf2(__expf(s[c][0]), __expf(s[c][1]));
            u.y = f2bf2(__expf(s[c][2]), __expf(s[c][3]));
            *(uint2*)&Pw[l16 * 72 + c * 16 + quad * 4] = u;
        }

        short8 pf[2];
        pf[0] = *(const short8*)&Pw[l16 * 72 + quad * 8];
        pf[1] = *(const short8*)&Pw[l16 * 72 + 32 + quad * 8];

        // ---- O += P V ; l += P * ones ----
        __builtin_amdgcn_s_setprio(1);
        #pragma unroll
        for (int p = 0; p < 2; ++p) {
            #pragma unroll
            for (int c = 0; c < 4; ++c)
                o[c] = __builtin_amdgcn_mfma_f32_16x16x32_bf16(pf[p], vf[c][p], o[c], 0, 0, 0);
            osum = __builtin_amdgcn_mfma_f32_16x16x32_bf16(pf[p], ones, osum, 0, 0, 0);
        }
        __builtin_amdgcn_s_setprio(0);
    }

    // ---- write partial TRANSPOSED: Opart[unit][col][row], packed b64 ----
    const size_t ub = (size_t)blockIdx.x * 4096;
    const int rbase = w * 16 + quad * 4;
    #pragma unroll
    for (int c = 0; c < 4; ++c) {
        uint2 u;
        u.x = f2bf2(o[c][0], o[c][1]);
        u.y = f2bf2(o[c][2], o[c][3]);
        *(uint2*)&Opart[ub + (size_t)(c * 16 + l16) * 64 + rbase] = u;
    }
    if (l16 == 0) {
        #pragma unroll
        for (int reg = 0; reg < 4; ++reg)
            ml[(size_t)blockIdx.x * 64 + rbase + reg] = osum[reg];
    }
}

// ---------------------------------------------------------------------------
// Kernel 3: merge partials (transposed Opart).  out = (sum O_p) / (sum l_p).
// ---------------------------------------------------------------------------
__global__ __launch_bounds__(256) void merge_kernel(
    const ushort* __restrict__ Opart, const float* __restrict__ ml,
    float* __restrict__ out)
{
    const int t    = threadIdx.x;
    const int gw   = blockIdx.x * 4 + (t >> 6);   // 0..2047
    const int lane = t & 63;                      // = output col
    const int b    = gw >> 8;
    const int v    = gw & 255;
    const int qt   = v >> 3;
    const int oct  = v & 7;

    int base, np;
    if (qt >= 24)      { base = (31 - qt) * 4;      np = 4; }
    else if (qt >= 16) { base = 32 + (23 - qt) * 3; np = 3; }
    else if (qt >= 8)  { base = 56 + (15 - qt) * 2; np = 2; }
    else               { base = 72 + (7 - qt);      np = 1; }

    float* obase = out + ((size_t)b * TT + qt * 64) * HH;

    #pragma unroll
    for (int rg = 0; rg < 2; ++rg) {
        const int row0 = oct * 8 + rg * 4;
        float dx = 0.f, dy = 0.f, dz = 0.f, dw = 0.f;
        float ax = 0.f, ay = 0.f, az = 0.f, aw = 0.f;
        for (int p = 0; p < np; ++p) {
            const int unit = (base + p) * 8 + b;
            float4 d = *(const float4*)&ml[(size_t)unit * 64 + row0];
            dx += d.x; dy += d.y; dz += d.z; dw += d.w;
            ushort4 ov = *(const ushort4*)&Opart[(size_t)unit * 4096 + lane * 64 + row0];
            ax += bf2f(ov.x); ay += bf2f(ov.y); az += bf2f(ov.z); aw += bf2f(ov.w);
        }
        obase[(size_t)(row0 + 0) * HH + lane] = ax / dx;
        obase[(size_t)(row0 + 1) * HH + lane] = ay / dy;
        obase[(size_t)(row0 + 2) * HH + lane] = az / dz;
        obase[(size_t)(row0 + 3) * HH + lane] = aw / dw;
    }
}

// ---------------------------------------------------------------------------
extern "C" void kernel_launch(void* const* d_in, const int* in_sizes, int n_in,
                              void* d_out, int out_size, void* d_ws, size_t ws_size,
                              hipStream_t stream)
{
    (void)in_sizes; (void)n_in; (void)out_size; (void)ws_size;
    const float* x  = (const float*)d_in[0];
    const float* Wq = (const float*)d_in[1];
    const float* Wk = (const float*)d_in[2];
    const float* Wv = (const float*)d_in[3];
    float* outp = (float*)d_out;

    // ws: WbT 384K | qb 2M | kbS 2M | vS 2M | Opart 5.24M | ml 160K (~11.8 MB)
    char* base = (char*)d_ws;
    ushort* WbT   = (ushort*)(base);
    ushort* qbuf  = (ushort*)(base + 393216);
    ushort* kbS   = qbuf + (size_t)BT * HH;
    ushort* vSb   = kbS + (size_t)BT * HH;
    ushort* Opart = vSb + (size_t)BT * HH;
    float*  ml    = (float*)((char*)Opart + (size_t)640 * 4096 * 2);

    wprep_kernel<<<dim3(48),  256, 0, stream>>>(Wq, Wk, Wv, WbT);
    qkv_kernel  <<<dim3(512), 256, 0, stream>>>(x, WbT, qbuf, kbS, vSb);
    attn_kernel <<<dim3(640), 256, 0, stream>>>(qbuf, kbS, vSb, Opart, ml);
    merge_kernel<<<dim3(512), 256, 0, stream>>>(Opart, ml, outp);
}